// Round 2
// baseline (3058.468 us; speedup 1.0000x reference)
//
#include <hip/hip_runtime.h>

#define N_ROWS 4096
#define D_DIM  2048
#define V_DIM  32000

typedef unsigned char u8;
typedef __attribute__((ext_vector_type(4))) int   i32x4;
typedef __attribute__((ext_vector_type(8))) int   i32x8;
typedef __attribute__((ext_vector_type(4))) float f32x4;

__device__ __forceinline__ unsigned pack4_fp8(float a, float b, float c, float d) {
    unsigned w = __builtin_amdgcn_cvt_pk_fp8_f32(a, b, 0, false);   // bytes 0,1
    w = __builtin_amdgcn_cvt_pk_fp8_f32(c, d, w, true);             // bytes 2,3
    return w;
}

// ---- zero the per-row accumulators ----
__global__ void init_acc(float* __restrict__ p, int n) {
    int i = blockIdx.x * blockDim.x + threadIdx.x;
    if (i < n) p[i] = 0.0f;
}

// ---- convert A fp32 [N,D] -> fp8 [N,D], LINEAR k packing (16B chunk i = bytes [16i,16i+16)) ----
__global__ void convert_a_fp8(const float4* __restrict__ in, uint4* __restrict__ out,
                              int nchunks) {
    int i = blockIdx.x * blockDim.x + threadIdx.x;
    int stride = gridDim.x * blockDim.x;
    for (; i < nchunks; i += stride) {
        float4 a0 = in[i * 4 + 0], a1 = in[i * 4 + 1];
        float4 a2 = in[i * 4 + 2], a3 = in[i * 4 + 3];
        uint4 o;
        o.x = pack4_fp8(a0.x, a0.y, a0.z, a0.w);
        o.y = pack4_fp8(a1.x, a1.y, a1.z, a1.w);
        o.z = pack4_fp8(a2.x, a2.y, a2.z, a2.w);
        o.w = pack4_fp8(a3.x, a3.y, a3.z, a3.w);
        out[i] = o;
    }
}

// ---- transpose-convert W fp32 [D,V] -> fp8 Wt [V,D], linear k (=D) packing.
// In-register 4x4 byte transpose via v_perm_b32; LDS staged as dwords
// (chunk-swizzled, 20-dword rows keep 16B alignment for the b128 read). ----
__global__ __launch_bounds__(256) void transpose_w_fp8(const float* __restrict__ W,
                                                       u8* __restrict__ Wt) {
    __shared__ alignas(16) unsigned tile[64][20];  // [v][d-dwords], 4 chunk slots @ dword 0/4/8/12
    const int tid = threadIdx.x;
    const int v0 = blockIdx.x * 64;
    const int d0 = blockIdx.y * 64;
    const int vch = (tid & 15) * 4;   // 4 consecutive v per thread
    const int dgi = tid >> 4;         // d-group: rows d0 + dgi*4 .. +3

    unsigned D[4];
#pragma unroll
    for (int j = 0; j < 4; ++j) {
        float4 w = *(const float4*)&W[(size_t)(d0 + dgi * 4 + j) * V_DIM + v0 + vch];
        D[j] = pack4_fp8(w.x, w.y, w.z, w.w);      // bytes = v..v+3 at row d
    }
    // 4x4 byte transpose: out[j] = {D0.b[j], D1.b[j], D2.b[j], D3.b[j]} (inc. d)
    unsigned p01l = __builtin_amdgcn_perm(D[1], D[0], 0x05010400u);
    unsigned p01h = __builtin_amdgcn_perm(D[1], D[0], 0x07030602u);
    unsigned p23l = __builtin_amdgcn_perm(D[3], D[2], 0x05010400u);
    unsigned p23h = __builtin_amdgcn_perm(D[3], D[2], 0x07030602u);
    unsigned o0 = __builtin_amdgcn_perm(p23l, p01l, 0x05040100u);
    unsigned o1 = __builtin_amdgcn_perm(p23l, p01l, 0x07060302u);
    unsigned o2 = __builtin_amdgcn_perm(p23h, p01h, 0x05040100u);
    unsigned o3 = __builtin_amdgcn_perm(p23h, p01h, 0x07060302u);

    // chunk c = dgi>>2 of row v stored at slot c ^ ((v>>2)&3)
    const int slot = (dgi >> 2) ^ ((vch >> 2) & 3);
    const int dpos = slot * 4 + (dgi & 3);
    tile[vch + 0][dpos] = o0;
    tile[vch + 1][dpos] = o1;
    tile[vch + 2][dpos] = o2;
    tile[vch + 3][dpos] = o3;
    __syncthreads();

    const int v = tid >> 2, q = tid & 3;
    const int sr = q ^ ((v >> 2) & 3);
    uint4 val = *(const uint4*)&tile[v][sr * 4];
    *(uint4*)&Wt[(size_t)(v0 + v) * D_DIM + d0 + q * 16] = val;
}

// ---- fused fp8 GEMM (MX-scaled 16x16x128 f8f6f4 MFMA, unit scales) + softcap + CE partials ----
// C-tile 128x128, BK=128 (one scaled MFMA per frag pair per kt), 4 waves 2x2, wave = 4x4 of 16x16.
// LDS row = 128 B = 4 granules of 32 B; granule g of row r at slot g ^ (r&3)
// -> each lane's 32 k-bytes are CONTIGUOUS in LDS: one i32x8 load = 2 adjacent ds_read_b128,
// no register-half merging (this is what spilled in the previous version).
__global__ __launch_bounds__(256) void gemm_ce(
    const u8* __restrict__ A, const u8* __restrict__ Wt,
    const int* __restrict__ targets,
    float* __restrict__ sumexp, float* __restrict__ sumlog, float* __restrict__ tlogit)
{
    __shared__ alignas(32) u8 lsA[128 * 128];
    __shared__ alignas(32) u8 lsB[128 * 128];

    const int tid   = threadIdx.x;
    const int lane  = tid & 63;
    const int wave  = tid >> 6;
    const int wr    = wave >> 1, wc = wave & 1;
    const int col16 = lane & 15, quad = lane >> 4;

    const int rowbase = blockIdx.x * 128;
    const int colbase = blockIdx.y * 128;

    f32x4 acc[4][4];
#pragma unroll
    for (int i = 0; i < 4; ++i)
#pragma unroll
        for (int j = 0; j < 4; ++j)
            acc[i][j] = (f32x4){0.f, 0.f, 0.f, 0.f};

    // staging: LDS chunk-slot = tid (linear dest, required by global_load_lds);
    // row r = (tid>>3)+32*i, within-row chunk-slot cs = tid&7.
    // inverse granule swizzle on the GLOBAL source: g = (cs>>1) ^ (r&3), chunk = 2g | (cs&1)
    const int r0     = tid >> 3;
    const int gchunk = ((((tid >> 1) & 3) ^ (r0 & 3)) << 1) | (tid & 1);
    const u8* gA = A  + (size_t)(rowbase + r0) * D_DIM + gchunk * 16;
    const u8* gB = Wt + (size_t)(colbase + r0) * D_DIM + gchunk * 16;
    u8* lA = &lsA[tid * 16];
    u8* lB = &lsB[tid * 16];

    // frag bases: row rA = wr*64 + mi*16 + col16 (rA&3 == col16&3);
    // lane's granule = quad -> LDS byte = rA*128 + (quad ^ (rA&3))*32, 32B contiguous
    const int sw2   = col16 & 3;
    const int baseA = (wr * 64 + col16) * 128 + ((quad ^ sw2) * 32);
    const int baseB = (wc * 64 + col16) * 128 + ((quad ^ sw2) * 32);
    const unsigned sc1 = 0x7F7F7F7Fu;   // e8m0 127 = 2^0 for all 4 blocks

    for (int kt = 0; kt < D_DIM / 128; ++kt) {
        const int ko = kt * 128;
#pragma unroll
        for (int i = 0; i < 4; ++i) {
            __builtin_amdgcn_global_load_lds(
                (const __attribute__((address_space(1))) void*)(gA + (size_t)i * 32 * D_DIM + ko),
                (__attribute__((address_space(3))) void*)(lA + i * 4096), 16, 0, 0);
            __builtin_amdgcn_global_load_lds(
                (const __attribute__((address_space(1))) void*)(gB + (size_t)i * 32 * D_DIM + ko),
                (__attribute__((address_space(3))) void*)(lB + i * 4096), 16, 0, 0);
        }
        __syncthreads();

        i32x8 bF[4];
#pragma unroll
        for (int ni = 0; ni < 4; ++ni)
            bF[ni] = *(const i32x8*)&lsB[baseB + ni * 2048];

#pragma unroll
        for (int mi = 0; mi < 4; ++mi) {
            i32x8 aF = *(const i32x8*)&lsA[baseA + mi * 2048];
#pragma unroll
            for (int ni = 0; ni < 4; ++ni)
                acc[mi][ni] = __builtin_amdgcn_mfma_scale_f32_16x16x128_f8f6f4(
                    aF, bF[ni], acc[mi][ni],
                    0, 0,              // cbsz=fp8(e4m3), blgp=fp8(e4m3)
                    0, sc1,            // scale A: 1.0
                    0, sc1);           // scale B: 1.0
        }
        __syncthreads();
    }

    // ---- epilogue: C/D layout col=lane&15, row=quad*4+reg (shape-determined, m89/m121) ----
#pragma unroll
    for (int mi = 0; mi < 4; ++mi) {
        int grows[4], tgts[4];
#pragma unroll
        for (int r = 0; r < 4; ++r) {
            grows[r] = rowbase + wr * 64 + mi * 16 + quad * 4 + r;
            tgts[r]  = targets[grows[r]];
        }
        float se[4] = {0.f, 0.f, 0.f, 0.f};
        float sl[4] = {0.f, 0.f, 0.f, 0.f};
#pragma unroll
        for (int ni = 0; ni < 4; ++ni) {
            int gcol = colbase + wc * 64 + ni * 16 + col16;
            f32x4 v = acc[mi][ni];
#pragma unroll
            for (int r = 0; r < 4; ++r) {
                float a  = v[r];
                float e2 = __expf(a * (2.0f / 30.0f));     // exp(2*a/30)
                float th = 1.0f - 2.0f / (e2 + 1.0f);      // tanh(a/30)
                float l  = 30.0f * th;
                float el = __expf(l);
                se[r] += el;
                sl[r] += l;
                if (tgts[r] == gcol) tlogit[grows[r]] = l; // unique writer
            }
        }
#pragma unroll
        for (int r = 0; r < 4; ++r) {
            float e = se[r], s = sl[r];
#pragma unroll
            for (int off = 1; off < 16; off <<= 1) {
                e += __shfl_xor(e, off);
                s += __shfl_xor(s, off);
            }
            if (col16 == 0) {
                atomicAdd(&sumexp[grows[r]], e);
                atomicAdd(&sumlog[grows[r]], s);
            }
        }
    }
}

// ---- final scalar reduction ----
__global__ void finalize(const float* __restrict__ sumexp, const float* __restrict__ sumlog,
                         const float* __restrict__ tlogit, const int* __restrict__ targets,
                         float* __restrict__ out)
{
    const int tid = threadIdx.x;
    float acc = 0.f, cnt = 0.f;
    for (int r = tid; r < N_ROWS; r += 256) {
        int tg = targets[r];
        if (tg != -100) {
            float lse    = __logf(sumexp[r]);
            float nll    = lse - tlogit[r];
            float smooth = lse - sumlog[r] * (1.0f / V_DIM);
            float ce     = 0.9f * nll + 0.1f * smooth;
            float z      = 1e-4f * lse * lse;
            acc += ce + z;
            cnt += 1.f;
        }
    }
#pragma unroll
    for (int off = 1; off < 64; off <<= 1) {
        acc += __shfl_xor(acc, off);
        cnt += __shfl_xor(cnt, off);
    }
    __shared__ float sa[4], sc[4];
    if ((tid & 63) == 0) { sa[tid >> 6] = acc; sc[tid >> 6] = cnt; }
    __syncthreads();
    if (tid == 0) {
        float t = sa[0] + sa[1] + sa[2] + sa[3];
        float c = sc[0] + sc[1] + sc[2] + sc[3];
        out[0] = t / c;
    }
}

extern "C" void kernel_launch(void* const* d_in, const int* in_sizes, int n_in,
                              void* d_out, int out_size, void* d_ws, size_t ws_size,
                              hipStream_t stream) {
    const float* A  = (const float*)d_in[0];   // [4096, 2048]
    const float* W  = (const float*)d_in[1];   // [2048, 32000]
    const int*   tg = (const int*)d_in[2];     // [4096]
    float* out = (float*)d_out;

    char* ws = (char*)d_ws;
    u8* A8 = (u8*)ws;
    size_t off = (size_t)N_ROWS * D_DIM;                    // 8 MB
    u8* Wt8 = (u8*)(ws + off);
    off += (size_t)V_DIM * D_DIM;                           // 64 MB
    float* sumexp = (float*)(ws + off); off += (size_t)N_ROWS * sizeof(float);
    float* sumlog = (float*)(ws + off); off += (size_t)N_ROWS * sizeof(float);
    float* tlog   = (float*)(ws + off); off += (size_t)N_ROWS * sizeof(float);

    init_acc<<<dim3((N_ROWS * 3 + 255) / 256), 256, 0, stream>>>(sumexp, N_ROWS * 3);
    convert_a_fp8<<<dim3(2048), 256, 0, stream>>>((const float4*)A, (uint4*)A8,
                                                  N_ROWS * D_DIM / 16);
    transpose_w_fp8<<<dim3(V_DIM / 64, D_DIM / 64), 256, 0, stream>>>(W, Wt8);
    gemm_ce<<<dim3(N_ROWS / 128, V_DIM / 128), 256, 0, stream>>>(A8, Wt8, tg,
                                                                 sumexp, sumlog, tlog);
    finalize<<<1, 256, 0, stream>>>(sumexp, sumlog, tlog, tg, out);
}

// Round 3
// 692.228 us; speedup vs baseline: 4.4183x; 4.4183x over previous
//
#include <hip/hip_runtime.h>

#define N_ROWS 4096
#define D_DIM  2048
#define V_DIM  32000

typedef unsigned char u8;
typedef __attribute__((ext_vector_type(4))) int   i32x4;
typedef __attribute__((ext_vector_type(8))) int   i32x8;
typedef __attribute__((ext_vector_type(4))) float f32x4;

__device__ __forceinline__ unsigned pack4_fp8(float a, float b, float c, float d) {
    unsigned w = __builtin_amdgcn_cvt_pk_fp8_f32(a, b, 0, false);   // bytes 0,1
    w = __builtin_amdgcn_cvt_pk_fp8_f32(c, d, w, true);             // bytes 2,3
    return w;
}

// ---- zero the per-row accumulators ----
__global__ void init_acc(float* __restrict__ p, int n) {
    int i = blockIdx.x * blockDim.x + threadIdx.x;
    if (i < n) p[i] = 0.0f;
}

// ---- convert A fp32 [N,D] -> fp8 [N,D], LINEAR k packing (16B chunk i = bytes [16i,16i+16)) ----
__global__ void convert_a_fp8(const float4* __restrict__ in, uint4* __restrict__ out,
                              int nchunks) {
    int i = blockIdx.x * blockDim.x + threadIdx.x;
    int stride = gridDim.x * blockDim.x;
    for (; i < nchunks; i += stride) {
        float4 a0 = in[i * 4 + 0], a1 = in[i * 4 + 1];
        float4 a2 = in[i * 4 + 2], a3 = in[i * 4 + 3];
        uint4 o;
        o.x = pack4_fp8(a0.x, a0.y, a0.z, a0.w);
        o.y = pack4_fp8(a1.x, a1.y, a1.z, a1.w);
        o.z = pack4_fp8(a2.x, a2.y, a2.z, a2.w);
        o.w = pack4_fp8(a3.x, a3.y, a3.z, a3.w);
        out[i] = o;
    }
}

// ---- transpose-convert W fp32 [D,V] -> fp8 Wt [V,D], linear k (=D) packing.
// In-register 4x4 byte transpose via v_perm_b32; LDS staged as dwords
// (chunk-swizzled, 20-dword rows keep 16B alignment for the b128 read). ----
__global__ __launch_bounds__(256) void transpose_w_fp8(const float* __restrict__ W,
                                                       u8* __restrict__ Wt) {
    __shared__ alignas(16) unsigned tile[64][20];  // [v][d-dwords], 4 chunk slots @ dword 0/4/8/12
    const int tid = threadIdx.x;
    const int v0 = blockIdx.x * 64;
    const int d0 = blockIdx.y * 64;
    const int vch = (tid & 15) * 4;   // 4 consecutive v per thread
    const int dgi = tid >> 4;         // d-group: rows d0 + dgi*4 .. +3

    unsigned D[4];
#pragma unroll
    for (int j = 0; j < 4; ++j) {
        float4 w = *(const float4*)&W[(size_t)(d0 + dgi * 4 + j) * V_DIM + v0 + vch];
        D[j] = pack4_fp8(w.x, w.y, w.z, w.w);      // bytes = v..v+3 at row d
    }
    // 4x4 byte transpose: out[j] = {D0.b[j], D1.b[j], D2.b[j], D3.b[j]} (inc. d)
    unsigned p01l = __builtin_amdgcn_perm(D[1], D[0], 0x05010400u);
    unsigned p01h = __builtin_amdgcn_perm(D[1], D[0], 0x07030602u);
    unsigned p23l = __builtin_amdgcn_perm(D[3], D[2], 0x05010400u);
    unsigned p23h = __builtin_amdgcn_perm(D[3], D[2], 0x07030602u);
    unsigned o0 = __builtin_amdgcn_perm(p23l, p01l, 0x05040100u);
    unsigned o1 = __builtin_amdgcn_perm(p23l, p01l, 0x07060302u);
    unsigned o2 = __builtin_amdgcn_perm(p23h, p01h, 0x05040100u);
    unsigned o3 = __builtin_amdgcn_perm(p23h, p01h, 0x07060302u);

    // chunk c = dgi>>2 of row v stored at slot c ^ ((v>>2)&3)
    const int slot = (dgi >> 2) ^ ((vch >> 2) & 3);
    const int dpos = slot * 4 + (dgi & 3);
    tile[vch + 0][dpos] = o0;
    tile[vch + 1][dpos] = o1;
    tile[vch + 2][dpos] = o2;
    tile[vch + 3][dpos] = o3;
    __syncthreads();

    const int v = tid >> 2, q = tid & 3;
    const int sr = q ^ ((v >> 2) & 3);
    uint4 val = *(const uint4*)&tile[v][sr * 4];
    *(uint4*)&Wt[(size_t)(v0 + v) * D_DIM + d0 + q * 16] = val;
}

// ---- fused fp8 GEMM (16x16x128 f8f6f4 MFMA via inline asm, implicit unit scales)
// + softcap + CE partials ----
// C-tile 128x128, BK=128 (one MFMA per frag pair per kt), 4 waves 2x2, wave = 4x4 of 16x16.
// LDS row = 128 B = 4 granules of 32 B; granule g of row r at slot g ^ (r&3)
// -> each lane's 32 k-bytes are CONTIGUOUS in LDS: one i32x8 load = 2 adjacent ds_read_b128.
// Inline asm bypasses the mfma_scale builtin lowering that spilled to scratch (r1/r2).
__global__ __launch_bounds__(256) void gemm_ce(
    const u8* __restrict__ A, const u8* __restrict__ Wt,
    const int* __restrict__ targets,
    float* __restrict__ sumexp, float* __restrict__ sumlog, float* __restrict__ tlogit)
{
    __shared__ alignas(32) u8 lsA[128 * 128];
    __shared__ alignas(32) u8 lsB[128 * 128];

    const int tid   = threadIdx.x;
    const int lane  = tid & 63;
    const int wave  = tid >> 6;
    const int wr    = wave >> 1, wc = wave & 1;
    const int col16 = lane & 15, quad = lane >> 4;

    const int rowbase = blockIdx.x * 128;
    const int colbase = blockIdx.y * 128;

    f32x4 acc[4][4];
#pragma unroll
    for (int i = 0; i < 4; ++i)
#pragma unroll
        for (int j = 0; j < 4; ++j)
            acc[i][j] = (f32x4){0.f, 0.f, 0.f, 0.f};

    // staging: LDS chunk-slot = tid (linear dest, required by global_load_lds);
    // row r = (tid>>3)+32*i, within-row chunk-slot cs = tid&7.
    // inverse granule swizzle on the GLOBAL source: g = (cs>>1) ^ (r&3), chunk = 2g | (cs&1)
    const int r0     = tid >> 3;
    const int gchunk = ((((tid >> 1) & 3) ^ (r0 & 3)) << 1) | (tid & 1);
    const u8* gA = A  + (size_t)(rowbase + r0) * D_DIM + gchunk * 16;
    const u8* gB = Wt + (size_t)(colbase + r0) * D_DIM + gchunk * 16;
    u8* lA = &lsA[tid * 16];
    u8* lB = &lsB[tid * 16];

    // frag bases: row rA = wr*64 + mi*16 + col16 (rA&3 == col16&3);
    // lane's granule = quad -> LDS byte = rA*128 + (quad ^ (rA&3))*32, 32B contiguous
    const int sw2   = col16 & 3;
    const int baseA = (wr * 64 + col16) * 128 + ((quad ^ sw2) * 32);
    const int baseB = (wc * 64 + col16) * 128 + ((quad ^ sw2) * 32);

    for (int kt = 0; kt < D_DIM / 128; ++kt) {
        const int ko = kt * 128;
#pragma unroll
        for (int i = 0; i < 4; ++i) {
            __builtin_amdgcn_global_load_lds(
                (const __attribute__((address_space(1))) void*)(gA + (size_t)i * 32 * D_DIM + ko),
                (__attribute__((address_space(3))) void*)(lA + i * 4096), 16, 0, 0);
            __builtin_amdgcn_global_load_lds(
                (const __attribute__((address_space(1))) void*)(gB + (size_t)i * 32 * D_DIM + ko),
                (__attribute__((address_space(3))) void*)(lB + i * 4096), 16, 0, 0);
        }
        __syncthreads();

        i32x8 bF[4];
#pragma unroll
        for (int ni = 0; ni < 4; ++ni)
            bF[ni] = *(const i32x8*)&lsB[baseB + ni * 2048];

#pragma unroll
        for (int mi = 0; mi < 4; ++mi) {
            i32x8 aF = *(const i32x8*)&lsA[baseA + mi * 2048];
#pragma unroll
            for (int ni = 0; ni < 4; ++ni)
                asm("v_mfma_f32_16x16x128_f8f6f4 %0, %1, %2, %0"
                    : "+v"(acc[mi][ni])
                    : "v"(aF), "v"(bF[ni]));
        }
        __syncthreads();
    }
    // MFMA-write -> VALU-read hazard cover (epilogue reads acc with VALU)
    asm volatile("s_nop 7\n\ts_nop 7");

    // ---- epilogue: C/D layout col=lane&15, row=quad*4+reg (shape-determined, m89/m121) ----
#pragma unroll
    for (int mi = 0; mi < 4; ++mi) {
        int grows[4], tgts[4];
#pragma unroll
        for (int r = 0; r < 4; ++r) {
            grows[r] = rowbase + wr * 64 + mi * 16 + quad * 4 + r;
            tgts[r]  = targets[grows[r]];
        }
        float se[4] = {0.f, 0.f, 0.f, 0.f};
        float sl[4] = {0.f, 0.f, 0.f, 0.f};
#pragma unroll
        for (int ni = 0; ni < 4; ++ni) {
            int gcol = colbase + wc * 64 + ni * 16 + col16;
            f32x4 v = acc[mi][ni];
#pragma unroll
            for (int r = 0; r < 4; ++r) {
                float a  = v[r];
                float e2 = __expf(a * (2.0f / 30.0f));     // exp(2*a/30)
                float th = 1.0f - 2.0f / (e2 + 1.0f);      // tanh(a/30)
                float l  = 30.0f * th;
                float el = __expf(l);
                se[r] += el;
                sl[r] += l;
                if (tgts[r] == gcol) tlogit[grows[r]] = l; // unique writer
            }
        }
#pragma unroll
        for (int r = 0; r < 4; ++r) {
            float e = se[r], s = sl[r];
#pragma unroll
            for (int off = 1; off < 16; off <<= 1) {
                e += __shfl_xor(e, off);
                s += __shfl_xor(s, off);
            }
            if (col16 == 0) {
                atomicAdd(&sumexp[grows[r]], e);
                atomicAdd(&sumlog[grows[r]], s);
            }
        }
    }
}

// ---- final scalar reduction ----
__global__ void finalize(const float* __restrict__ sumexp, const float* __restrict__ sumlog,
                         const float* __restrict__ tlogit, const int* __restrict__ targets,
                         float* __restrict__ out)
{
    const int tid = threadIdx.x;
    float acc = 0.f, cnt = 0.f;
    for (int r = tid; r < N_ROWS; r += 256) {
        int tg = targets[r];
        if (tg != -100) {
            float lse    = __logf(sumexp[r]);
            float nll    = lse - tlogit[r];
            float smooth = lse - sumlog[r] * (1.0f / V_DIM);
            float ce     = 0.9f * nll + 0.1f * smooth;
            float z      = 1e-4f * lse * lse;
            acc += ce + z;
            cnt += 1.f;
        }
    }
#pragma unroll
    for (int off = 1; off < 64; off <<= 1) {
        acc += __shfl_xor(acc, off);
        cnt += __shfl_xor(cnt, off);
    }
    __shared__ float sa[4], sc[4];
    if ((tid & 63) == 0) { sa[tid >> 6] = acc; sc[tid >> 6] = cnt; }
    __syncthreads();
    if (tid == 0) {
        float t = sa[0] + sa[1] + sa[2] + sa[3];
        float c = sc[0] + sc[1] + sc[2] + sc[3];
        out[0] = t / c;
    }
}

extern "C" void kernel_launch(void* const* d_in, const int* in_sizes, int n_in,
                              void* d_out, int out_size, void* d_ws, size_t ws_size,
                              hipStream_t stream) {
    const float* A  = (const float*)d_in[0];   // [4096, 2048]
    const float* W  = (const float*)d_in[1];   // [2048, 32000]
    const int*   tg = (const int*)d_in[2];     // [4096]
    float* out = (float*)d_out;

    char* ws = (char*)d_ws;
    u8* A8 = (u8*)ws;
    size_t off = (size_t)N_ROWS * D_DIM;                    // 8 MB
    u8* Wt8 = (u8*)(ws + off);
    off += (size_t)V_DIM * D_DIM;                           // 64 MB
    float* sumexp = (float*)(ws + off); off += (size_t)N_ROWS * sizeof(float);
    float* sumlog = (float*)(ws + off); off += (size_t)N_ROWS * sizeof(float);
    float* tlog   = (float*)(ws + off); off += (size_t)N_ROWS * sizeof(float);

    init_acc<<<dim3((N_ROWS * 3 + 255) / 256), 256, 0, stream>>>(sumexp, N_ROWS * 3);
    convert_a_fp8<<<dim3(2048), 256, 0, stream>>>((const float4*)A, (uint4*)A8,
                                                  N_ROWS * D_DIM / 16);
    transpose_w_fp8<<<dim3(V_DIM / 64, D_DIM / 64), 256, 0, stream>>>(W, Wt8);
    gemm_ce<<<dim3(N_ROWS / 128, V_DIM / 128), 256, 0, stream>>>(A8, Wt8, tg,
                                                                 sumexp, sumlog, tlog);
    finalize<<<1, 256, 0, stream>>>(sumexp, sumlog, tlog, tg, out);
}